// Round 2
// baseline (152.412 us; speedup 1.0000x reference)
//
#include <hip/hip_runtime.h>
#include <hip/hip_bf16.h>

#define NFFT 1024
#define HOP 256
#define NB 16
#define NF 513
#define NT 1024
#define KA 576                     // padded K: 9*64 (freqs 0..512 + zeros)
#define MM (NB*NT)                 // 16384
#define LOUT ((NT-1)*HOP + NFFT)   // 262912
#define CQ (2.0f/(3.0f*1024.0f))   // coeff/NFFT = (HOP/sum(win^2))/1024

typedef __bf16 bf16x8 __attribute__((ext_vector_type(8)));
typedef float f32x4 __attribute__((ext_vector_type(4)));

__device__ __forceinline__ void gload_lds16(const void* g, void* l) {
  __builtin_amdgcn_global_load_lds(
      (const __attribute__((address_space(1))) void*)g,
      (__attribute__((address_space(3))) void*)l, 16, 0, 0);
}

// Bc[n][f] = scale_f*cos(2*pi*f*n/1024)*CQ ; Bs[n][f] = scale_f*sin(...)*CQ
// n in 0..511, f in 0..575 (zeros for f>512).
__global__ void build_B(__hip_bfloat16* __restrict__ Bc, __hip_bfloat16* __restrict__ Bs) {
  int idx = blockIdx.x * 256 + threadIdx.x;   // grid covers 512*576
  int n = idx / KA;
  int f = idx - n * KA;
  float c = 0.f, s = 0.f;
  if (f <= 512) {
    int ph = (f * n) & (NFFT - 1);            // exact mod-1024 phase
    const float w0 = 6.283185307179586f / NFFT;
    float si, co;
    __sincosf((float)ph * w0, &si, &co);
    float sc = (f == 0 || f == 512) ? 1.f : 2.f;
    c = co * sc * CQ;
    s = si * sc * CQ;
  }
  Bc[idx] = __float2bfloat16(c);
  Bs[idx] = __float2bfloat16(s);
}

// Are[b*1024+t][f] = x[b][f][t][0], Aim[...] = x[b][f][t][1]; zero pad f>=513.
__global__ void pack_a(const float* __restrict__ x,
                       __hip_bfloat16* __restrict__ Are, __hip_bfloat16* __restrict__ Aim) {
  __shared__ float2 tile[64][65];
  int b = blockIdx.z, f0 = blockIdx.y * 64, t0 = blockIdx.x * 64;
  int tid = threadIdx.x;
  int tl = tid & 63, th = tid >> 6;
#pragma unroll
  for (int r = 0; r < 16; ++r) {
    int fl = r * 4 + th;
    int f = f0 + fl;
    float2 v = make_float2(0.f, 0.f);
    if (f < NF)
      v = *(const float2*)(x + (((size_t)b * NF + f) * NT + (t0 + tl)) * 2);
    tile[fl][tl] = v;
  }
  __syncthreads();
#pragma unroll
  for (int r = 0; r < 16; ++r) {
    int tloc = r * 4 + th;
    size_t row = (size_t)(b * NT + t0 + tloc) * KA;
    float2 v = tile[tl][tloc];
    Are[row + f0 + tl] = __float2bfloat16(v.x);
    Aim[row + f0 + tl] = __float2bfloat16(v.y);
  }
}

// U[m][n] = sum_f Are[m][f]*Bc[n][f]; V[m][n] = sum_f Aim[m][f]*Bs[n][f]
// epilogue: out[b][t*256 + n]     += win[n]*(U-V)
//           out[b][t*256 + 1024-n]+= win[n]*(U+V)   (n>=1; win symmetric)
__global__ __launch_bounds__(256) void gemm_uv(
    const __hip_bfloat16* __restrict__ Are, const __hip_bfloat16* __restrict__ Aim,
    const __hip_bfloat16* __restrict__ Bc, const __hip_bfloat16* __restrict__ Bs,
    float* __restrict__ out) {
  __shared__ __align__(16) __hip_bfloat16 sAr[128 * 64];
  __shared__ __align__(16) __hip_bfloat16 sAi[128 * 64];
  __shared__ __align__(16) __hip_bfloat16 sBc[128 * 64];
  __shared__ __align__(16) __hip_bfloat16 sBs[128 * 64];
  int tid = threadIdx.x;
  int lane = tid & 63;
  int wv = tid >> 6;
  int wmo = (wv >> 1) * 64;
  int wno = (wv & 1) * 64;
  int M0 = blockIdx.x * 128;
  int N0 = blockIdx.y * 128;

  f32x4 aU[4][4] = {};
  f32x4 aV[4][4] = {};
  const int kl = (tid & 7) * 8;

  for (int kt = 0; kt < KA / 64; ++kt) {
    if (kt) __syncthreads();
    int k0 = kt * 64;
#pragma unroll
    for (int seg = 0; seg < 4; ++seg) {
      int ml = seg * 32 + (tid >> 3);
      size_t ga = (size_t)(M0 + ml) * KA + k0 + kl;
      size_t gb = (size_t)(N0 + ml) * KA + k0 + kl;
      int lo = ml * 64 + kl;
      gload_lds16(Are + ga, &sAr[lo]);
      gload_lds16(Aim + ga, &sAi[lo]);
      gload_lds16(Bc + gb, &sBc[lo]);
      gload_lds16(Bs + gb, &sBs[lo]);
    }
    __syncthreads();
#pragma unroll
    for (int ks = 0; ks < 2; ++ks) {
      int krow = ks * 32 + (lane >> 4) * 8;
      bf16x8 af[4], bfr[4];
#pragma unroll
      for (int mi = 0; mi < 4; ++mi)
        af[mi] = *(const bf16x8*)&sAr[(wmo + mi * 16 + (lane & 15)) * 64 + krow];
#pragma unroll
      for (int ni = 0; ni < 4; ++ni)
        bfr[ni] = *(const bf16x8*)&sBc[(wno + ni * 16 + (lane & 15)) * 64 + krow];
#pragma unroll
      for (int mi = 0; mi < 4; ++mi)
#pragma unroll
        for (int ni = 0; ni < 4; ++ni)
          aU[mi][ni] = __builtin_amdgcn_mfma_f32_16x16x32_bf16(
              af[mi], bfr[ni], aU[mi][ni], 0, 0, 0);
#pragma unroll
      for (int mi = 0; mi < 4; ++mi)
        af[mi] = *(const bf16x8*)&sAi[(wmo + mi * 16 + (lane & 15)) * 64 + krow];
#pragma unroll
      for (int ni = 0; ni < 4; ++ni)
        bfr[ni] = *(const bf16x8*)&sBs[(wno + ni * 16 + (lane & 15)) * 64 + krow];
#pragma unroll
      for (int mi = 0; mi < 4; ++mi)
#pragma unroll
        for (int ni = 0; ni < 4; ++ni)
          aV[mi][ni] = __builtin_amdgcn_mfma_f32_16x16x32_bf16(
              af[mi], bfr[ni], aV[mi][ni], 0, 0, 0);
    }
  }

  const float w0 = 6.283185307179586f / NFFT;
#pragma unroll
  for (int mi = 0; mi < 4; ++mi) {
#pragma unroll
    for (int ni = 0; ni < 4; ++ni) {
      int n = N0 + wno + ni * 16 + (lane & 15);
      float wn = 0.5f - 0.5f * __cosf((float)n * w0);
#pragma unroll
      for (int r = 0; r < 4; ++r) {
        int m = M0 + wmo + mi * 16 + (lane >> 4) * 4 + r;
        int b = m >> 10, t = m & 1023;
        float* op = out + (size_t)b * LOUT + t * HOP;
        float U = aU[mi][ni][r], V = aV[mi][ni][r];
        atomicAdd(op + n, wn * (U - V));
        if (n) atomicAdd(op + 1024 - n, wn * (U + V));
      }
    }
  }
}

// Nyquist column n=512: frame[t][512] = win[512] * sum_f scale_f*(-1)^f*re[f]*CQ
// win[512]=1. weight: f=0 -> +1, f=512 -> +1, f odd -> -2, f even -> +2.
__global__ void nyq(const __hip_bfloat16* __restrict__ Are, float* __restrict__ out) {
  int lane = threadIdx.x & 63;
  int row = blockIdx.x * 4 + (threadIdx.x >> 6);
  const bf16x8 v = *(const bf16x8*)&Are[(size_t)row * KA + lane * 8];
  float s = 0.f;
#pragma unroll
  for (int e = 0; e < 8; ++e) {
    int f = lane * 8 + e;
    float w = (f == 0) ? 1.f : ((f & 1) ? -2.f : 2.f);
    s += w * __bfloat162float(v[e]);
  }
  if (lane == 0) s += __bfloat162float(Are[(size_t)row * KA + 512]);
#pragma unroll
  for (int off = 32; off >= 1; off >>= 1) s += __shfl_xor(s, off, 64);
  if (lane == 0) {
    int b = row >> 10, t = row & 1023;
    atomicAdd(out + (size_t)b * LOUT + t * HOP + 512, s * CQ);
  }
}

extern "C" void kernel_launch(void* const* d_in, const int* in_sizes, int n_in,
                              void* d_out, int out_size, void* d_ws, size_t ws_size,
                              hipStream_t stream) {
  (void)in_sizes; (void)n_in; (void)ws_size;
  const float* x = (const float*)d_in[0];
  float* out = (float*)d_out;
  char* ws = (char*)d_ws;
  __hip_bfloat16* Are = (__hip_bfloat16*)ws;
  __hip_bfloat16* Aim = (__hip_bfloat16*)(ws + (size_t)MM * KA * 2);
  __hip_bfloat16* Bc  = (__hip_bfloat16*)(ws + (size_t)MM * KA * 4);
  __hip_bfloat16* Bs  = (__hip_bfloat16*)(ws + (size_t)MM * KA * 4 + (size_t)512 * KA * 2);

  hipMemsetAsync(d_out, 0, (size_t)out_size * sizeof(float), stream);
  build_B<<<dim3(512 * KA / 256), dim3(256), 0, stream>>>(Bc, Bs);
  pack_a<<<dim3(16, 9, 16), dim3(256), 0, stream>>>(x, Are, Aim);
  gemm_uv<<<dim3(MM / 128, 4), dim3(256), 0, stream>>>(Are, Aim, Bc, Bs, out);
  nyq<<<dim3(MM / 4), dim3(256), 0, stream>>>(Are, out);
}

// Round 3
// 105.159 us; speedup vs baseline: 1.4493x; 1.4493x over previous
//
#include <hip/hip_runtime.h>
#include <hip/hip_bf16.h>

#define NFFT 1024
#define HOP 256
#define NB 16
#define NF 513
#define NT 1024
#define KA 576                     // padded K: 9*64 (freqs 0..512 + zeros)
#define MM (NB*NT)                 // 16384
#define LOUT ((NT-1)*HOP + NFFT)   // 262912
#define CQ (2.0f/(3.0f*1024.0f))   // coeff/NFFT = (HOP/sum(win^2))/1024

typedef __bf16 bf16x8 __attribute__((ext_vector_type(8)));
typedef float f32x4 __attribute__((ext_vector_type(4)));

__device__ __forceinline__ void gload_lds16(const void* g, void* l) {
  __builtin_amdgcn_global_load_lds(
      (const __attribute__((address_space(1))) void*)g,
      (__attribute__((address_space(3))) void*)l, 16, 0, 0);
}

// Bc[n][f] = scale_f*cos(2*pi*f*n/1024)*CQ ; Bs[n][f] = scale_f*sin(...)*CQ
__global__ void build_B(__hip_bfloat16* __restrict__ Bc, __hip_bfloat16* __restrict__ Bs) {
  int idx = blockIdx.x * 256 + threadIdx.x;
  int n = idx / KA;
  int f = idx - n * KA;
  float c = 0.f, s = 0.f;
  if (f <= 512) {
    int ph = (f * n) & (NFFT - 1);
    const float w0 = 6.283185307179586f / NFFT;
    float si, co;
    __sincosf((float)ph * w0, &si, &co);
    float sc = (f == 0 || f == 512) ? 1.f : 2.f;
    c = co * sc * CQ;
    s = si * sc * CQ;
  }
  Bc[idx] = __float2bfloat16(c);
  Bs[idx] = __float2bfloat16(s);
}

// Are[b*1024+t][f] = x[b][f][t][0], Aim[...] = x[b][f][t][1]; zero pad f>=513.
__global__ void pack_a(const float* __restrict__ x,
                       __hip_bfloat16* __restrict__ Are, __hip_bfloat16* __restrict__ Aim) {
  __shared__ float2 tile[64][65];
  int b = blockIdx.z, f0 = blockIdx.y * 64, t0 = blockIdx.x * 64;
  int tid = threadIdx.x;
  int tl = tid & 63, th = tid >> 6;
#pragma unroll
  for (int r = 0; r < 16; ++r) {
    int fl = r * 4 + th;
    int f = f0 + fl;
    float2 v = make_float2(0.f, 0.f);
    if (f < NF)
      v = *(const float2*)(x + (((size_t)b * NF + f) * NT + (t0 + tl)) * 2);
    tile[fl][tl] = v;
  }
  __syncthreads();
#pragma unroll
  for (int r = 0; r < 16; ++r) {
    int tloc = r * 4 + th;
    size_t row = (size_t)(b * NT + t0 + tloc) * KA;
    float2 v = tile[tl][tloc];
    Are[row + f0 + tl] = __float2bfloat16(v.x);
    Aim[row + f0 + tl] = __float2bfloat16(v.y);
  }
}

// U = Are*Bc^T, V = Aim*Bs^T; frames[m][n] = win[n]*(U-V), frames[m][1024-n] = win[n]*(U+V)
__global__ __launch_bounds__(256) void gemm_uv(
    const __hip_bfloat16* __restrict__ Are, const __hip_bfloat16* __restrict__ Aim,
    const __hip_bfloat16* __restrict__ Bc, const __hip_bfloat16* __restrict__ Bs,
    float* __restrict__ frames, __hip_bfloat16* __restrict__ framesh, int bf16f) {
  __shared__ __align__(16) __hip_bfloat16 sAr[128 * 64];
  __shared__ __align__(16) __hip_bfloat16 sAi[128 * 64];
  __shared__ __align__(16) __hip_bfloat16 sBc[128 * 64];
  __shared__ __align__(16) __hip_bfloat16 sBs[128 * 64];
  int tid = threadIdx.x;
  int lane = tid & 63;
  int wv = tid >> 6;
  int wmo = (wv >> 1) * 64;
  int wno = (wv & 1) * 64;
  int M0 = blockIdx.x * 128;
  int N0 = blockIdx.y * 128;

  f32x4 aU[4][4] = {};
  f32x4 aV[4][4] = {};
  const int kl = (tid & 7) * 8;

  for (int kt = 0; kt < KA / 64; ++kt) {
    if (kt) __syncthreads();
    int k0 = kt * 64;
#pragma unroll
    for (int seg = 0; seg < 4; ++seg) {
      int ml = seg * 32 + (tid >> 3);
      size_t ga = (size_t)(M0 + ml) * KA + k0 + kl;
      size_t gb = (size_t)(N0 + ml) * KA + k0 + kl;
      int lo = ml * 64 + kl;
      gload_lds16(Are + ga, &sAr[lo]);
      gload_lds16(Aim + ga, &sAi[lo]);
      gload_lds16(Bc + gb, &sBc[lo]);
      gload_lds16(Bs + gb, &sBs[lo]);
    }
    __syncthreads();
#pragma unroll
    for (int ks = 0; ks < 2; ++ks) {
      int krow = ks * 32 + (lane >> 4) * 8;
      bf16x8 af[4], bfr[4];
#pragma unroll
      for (int mi = 0; mi < 4; ++mi)
        af[mi] = *(const bf16x8*)&sAr[(wmo + mi * 16 + (lane & 15)) * 64 + krow];
#pragma unroll
      for (int ni = 0; ni < 4; ++ni)
        bfr[ni] = *(const bf16x8*)&sBc[(wno + ni * 16 + (lane & 15)) * 64 + krow];
#pragma unroll
      for (int mi = 0; mi < 4; ++mi)
#pragma unroll
        for (int ni = 0; ni < 4; ++ni)
          aU[mi][ni] = __builtin_amdgcn_mfma_f32_16x16x32_bf16(
              af[mi], bfr[ni], aU[mi][ni], 0, 0, 0);
#pragma unroll
      for (int mi = 0; mi < 4; ++mi)
        af[mi] = *(const bf16x8*)&sAi[(wmo + mi * 16 + (lane & 15)) * 64 + krow];
#pragma unroll
      for (int ni = 0; ni < 4; ++ni)
        bfr[ni] = *(const bf16x8*)&sBs[(wno + ni * 16 + (lane & 15)) * 64 + krow];
#pragma unroll
      for (int mi = 0; mi < 4; ++mi)
#pragma unroll
        for (int ni = 0; ni < 4; ++ni)
          aV[mi][ni] = __builtin_amdgcn_mfma_f32_16x16x32_bf16(
              af[mi], bfr[ni], aV[mi][ni], 0, 0, 0);
    }
  }

  const float w0 = 6.283185307179586f / NFFT;
#pragma unroll
  for (int mi = 0; mi < 4; ++mi) {
#pragma unroll
    for (int ni = 0; ni < 4; ++ni) {
      int n = N0 + wno + ni * 16 + (lane & 15);
      float wn = 0.5f - 0.5f * __cosf((float)n * w0);
#pragma unroll
      for (int r = 0; r < 4; ++r) {
        int m = M0 + wmo + mi * 16 + (lane >> 4) * 4 + r;
        float U = aU[mi][ni][r], V = aV[mi][ni][r];
        float f0v = wn * (U - V);
        float f1v = wn * (U + V);
        if (!bf16f) {
          float* fp = frames + (size_t)m * NFFT;
          fp[n] = f0v;
          if (n) fp[1024 - n] = f1v;
        } else {
          __hip_bfloat16* fp = framesh + (size_t)m * NFFT;
          fp[n] = __float2bfloat16(f0v);
          if (n) fp[1024 - n] = __float2bfloat16(f1v);
        }
      }
    }
  }
}

// Nyquist column: frames[m][512] = CQ * (re[0] + re[512] + sum_{f=1..511} (-1)^f*2*re[f])
__global__ void nyq(const __hip_bfloat16* __restrict__ Are, float* __restrict__ frames,
                    __hip_bfloat16* __restrict__ framesh, int bf16f) {
  int lane = threadIdx.x & 63;
  int row = blockIdx.x * 4 + (threadIdx.x >> 6);
  const bf16x8 v = *(const bf16x8*)&Are[(size_t)row * KA + lane * 8];
  float s = 0.f;
#pragma unroll
  for (int e = 0; e < 8; ++e) {
    int f = lane * 8 + e;
    float w = (f == 0) ? 1.f : ((f & 1) ? -2.f : 2.f);
    s += w * __bfloat162float(v[e]);
  }
  if (lane == 0) s += __bfloat162float(Are[(size_t)row * KA + 512]);
#pragma unroll
  for (int off = 32; off >= 1; off >>= 1) s += __shfl_xor(s, off, 64);
  if (lane == 0) {
    if (!bf16f) frames[(size_t)row * NFFT + 512] = s * CQ;
    else framesh[(size_t)row * NFFT + 512] = __float2bfloat16(s * CQ);
  }
}

// out[b][l] = sum over t with 0 <= l - 256t < 1024 of frames[b][t][l-256t]
__global__ void ola(const float* __restrict__ frames, const __hip_bfloat16* __restrict__ framesh,
                    int bf16f, float* __restrict__ out, int total) {
  int idx = blockIdx.x * blockDim.x + threadIdx.x;
  int stride = gridDim.x * blockDim.x;
  for (; idx < total; idx += stride) {
    int b = idx / LOUT;
    int l = idx - b * LOUT;
    int thi = l >> 8; if (thi > NT - 1) thi = NT - 1;
    int tlo = (l - (NFFT - HOP)) >> 8; if (tlo < 0) tlo = 0;
    float s = 0.f;
    if (!bf16f) {
      for (int t = tlo; t <= thi; ++t)
        s += frames[((size_t)b * NT + t) * NFFT + (l - t * HOP)];
    } else {
      for (int t = tlo; t <= thi; ++t)
        s += __bfloat162float(framesh[((size_t)b * NT + t) * NFFT + (l - t * HOP)]);
    }
    out[idx] = s;
  }
}

extern "C" void kernel_launch(void* const* d_in, const int* in_sizes, int n_in,
                              void* d_out, int out_size, void* d_ws, size_t ws_size,
                              hipStream_t stream) {
  (void)in_sizes; (void)n_in; (void)out_size;
  const float* x = (const float*)d_in[0];
  float* out = (float*)d_out;
  char* ws = (char*)d_ws;
  __hip_bfloat16* Are = (__hip_bfloat16*)ws;
  __hip_bfloat16* Aim = (__hip_bfloat16*)(ws + (size_t)MM * KA * 2);
  __hip_bfloat16* Bc  = (__hip_bfloat16*)(ws + (size_t)MM * KA * 4);
  __hip_bfloat16* Bs  = (__hip_bfloat16*)(ws + (size_t)MM * KA * 4 + (size_t)512 * KA * 2);
  size_t base = (size_t)MM * KA * 4 + (size_t)512 * KA * 4;
  float* frames = (float*)(ws + base);
  __hip_bfloat16* framesh = (__hip_bfloat16*)(ws + base);
  int bf16f = (ws_size < base + (size_t)MM * NFFT * 4) ? 1 : 0;

  build_B<<<dim3(512 * KA / 256), dim3(256), 0, stream>>>(Bc, Bs);
  pack_a<<<dim3(16, 9, 16), dim3(256), 0, stream>>>(x, Are, Aim);
  nyq<<<dim3(MM / 4), dim3(256), 0, stream>>>(Are, frames, framesh, bf16f);
  gemm_uv<<<dim3(MM / 128, 4), dim3(256), 0, stream>>>(Are, Aim, Bc, Bs, frames, framesh, bf16f);
  ola<<<dim3(2048), dim3(256), 0, stream>>>(frames, framesh, bf16f, out, NB * LOUT);
}

// Round 4
// 87.619 us; speedup vs baseline: 1.7395x; 1.2002x over previous
//
#include <hip/hip_runtime.h>
#include <hip/hip_bf16.h>

#define NFFT 1024
#define HOP 256
#define NB 16
#define NT 1024
#define KA 512                     // K = freqs 0..511 (f=512 via re512 rank-1 term)
#define MM (NB*NT)                 // 16384
#define LOUT ((NT-1)*HOP + NFFT)   // 262912
#define CQ (2.0f/(3.0f*1024.0f))   // (HOP/sum(win^2))/NFFT

typedef __bf16 bf16x8 __attribute__((ext_vector_type(8)));
typedef float f32x4 __attribute__((ext_vector_type(4)));

__device__ __forceinline__ void gload_lds16(const void* g, void* l) {
  __builtin_amdgcn_global_load_lds(
      (const __attribute__((address_space(1))) void*)g,
      (__attribute__((address_space(3))) void*)l, 16, 0, 0);
}

// Bc[n][f] = sc_f*cos(2pi f n/1024)*CQ*win[n]; Bs likewise with sin. win folded in.
// s_tab[n] = (-1)^n * win[n] * CQ   (the f=512 rank-1 column factor)
__global__ void build_B(__hip_bfloat16* __restrict__ Bc, __hip_bfloat16* __restrict__ Bs,
                        float* __restrict__ s_tab) {
  int idx = blockIdx.x * 256 + threadIdx.x;   // 512*512
  int n = idx >> 9;
  int f = idx & 511;
  int ph = (f * n) & 1023;
  const float w0 = 6.283185307179586f / 1024.f;
  float si, co;
  __sincosf((float)ph * w0, &si, &co);
  float wn = 0.5f - 0.5f * __cosf((float)n * w0);
  float sc = (f == 0) ? 1.f : 2.f;
  float b = sc * CQ * wn;
  Bc[idx] = __float2bfloat16(co * b);
  Bs[idx] = __float2bfloat16(si * b);
  if (idx < 512) {
    float wn2 = 0.5f - 0.5f * __cosf((float)idx * w0);
    s_tab[idx] = ((idx & 1) ? -1.f : 1.f) * wn2 * CQ;
  }
}

// Are[b*1024+t][f] = x[b][f][t][0], Aim = [..][1]; re512[m] = x[b][512][t][0]
__global__ void pack_a(const float* __restrict__ x,
                       __hip_bfloat16* __restrict__ Are, __hip_bfloat16* __restrict__ Aim,
                       float* __restrict__ re512) {
  __shared__ float2 tile[64][65];
  int b = blockIdx.z, f0 = blockIdx.y * 64, t0 = blockIdx.x * 64;
  int tid = threadIdx.x;
  int tl = tid & 63, th = tid >> 6;
#pragma unroll
  for (int r = 0; r < 16; ++r) {
    int fl = r * 4 + th;
    tile[fl][tl] = *(const float2*)(x + (((size_t)b * 513 + f0 + fl) * 1024 + (t0 + tl)) * 2);
  }
  __syncthreads();
#pragma unroll
  for (int r = 0; r < 16; ++r) {
    int tloc = r * 4 + th;
    size_t row = (size_t)(b * 1024 + t0 + tloc) * KA;
    float2 v = tile[tl][tloc];
    Are[row + f0 + tl] = __float2bfloat16(v.x);
    Aim[row + f0 + tl] = __float2bfloat16(v.y);
  }
  if (blockIdx.y == 0 && tid < 64)
    re512[b * 1024 + t0 + tid] = x[(((size_t)b * 513 + 512) * 1024 + t0 + tid) * 2];
}

// fr512[m] = CQ * (re0 + re512 + sum_{f=1..511} 2*(-1)^f re_f)   (win[512]=1)
__global__ void nyq(const __hip_bfloat16* __restrict__ Are, const float* __restrict__ re512,
                    float* __restrict__ fr512) {
  int tid = threadIdx.x;
  int lane = tid & 63;
  int row = blockIdx.x * 4 + (tid >> 6);
  const bf16x8 v = *(const bf16x8*)&Are[(size_t)row * KA + lane * 8];
  float s = 0.f;
#pragma unroll
  for (int e = 0; e < 8; ++e) {
    int f = lane * 8 + e;
    float w = (f == 0) ? 1.f : ((f & 1) ? -2.f : 2.f);
    s += w * __bfloat162float(v[e]);
  }
#pragma unroll
  for (int off = 32; off >= 1; off >>= 1) s += __shfl_xor(s, off, 64);
  if (lane == 0) fr512[row] = (s + re512[row]) * CQ;
}

// U = Are*Bc^T, V = Aim*Bs^T (win folded in B). frames0[m][n] = U-V+re512*s[n] (n<512),
// frames1[m][511-n] = U+V+re512*s[n]  (maps j=1024-n>512 to col j-513).
__global__ __launch_bounds__(256) void gemm_uv(
    const __hip_bfloat16* __restrict__ Are, const __hip_bfloat16* __restrict__ Aim,
    const __hip_bfloat16* __restrict__ Bc, const __hip_bfloat16* __restrict__ Bs,
    const float* __restrict__ re512, const float* __restrict__ s_tab,
    __hip_bfloat16* __restrict__ frames0, __hip_bfloat16* __restrict__ frames1) {
  __shared__ __align__(16) __hip_bfloat16 smem[32768];  // 2 bufs x 4 tiles x 128x32
  int tid = threadIdx.x;
  int lane = tid & 63;
  int wv = tid >> 6;
  int wmo = (wv >> 1) * 64;
  int wno = (wv & 1) * 64;
  int M0 = blockIdx.x * 128;
  int N0 = blockIdx.y * 128;

  f32x4 aU[4][4] = {};
  f32x4 aV[4][4] = {};

  const int srow = tid >> 2;       // 0..63
  const int sch = (tid & 3) * 8;   // 0,8,16,24

  // prologue: stage kt=0 into buf0
#pragma unroll
  for (int p = 0; p < 2; ++p) {
    int row = p * 64 + srow;
    size_t ga = (size_t)(M0 + row) * KA + sch;
    size_t gb = (size_t)(N0 + row) * KA + sch;
    int lo = row * 32 + sch;
    gload_lds16(Are + ga, &smem[lo]);
    gload_lds16(Aim + ga, &smem[4096 + lo]);
    gload_lds16(Bc + gb, &smem[8192 + lo]);
    gload_lds16(Bs + gb, &smem[12288 + lo]);
  }
  __syncthreads();

  for (int kt = 0; kt < 16; ++kt) {
    int cur = (kt & 1) * 16384;
    if (kt + 1 < 16) {                     // issue next-tile stage BEFORE compute
      int nxt = cur ^ 16384;
      int k0 = (kt + 1) * 32;
#pragma unroll
      for (int p = 0; p < 2; ++p) {
        int row = p * 64 + srow;
        size_t ga = (size_t)(M0 + row) * KA + k0 + sch;
        size_t gb = (size_t)(N0 + row) * KA + k0 + sch;
        int lo = row * 32 + sch;
        gload_lds16(Are + ga, &smem[nxt + lo]);
        gload_lds16(Aim + ga, &smem[nxt + 4096 + lo]);
        gload_lds16(Bc + gb, &smem[nxt + 8192 + lo]);
        gload_lds16(Bs + gb, &smem[nxt + 12288 + lo]);
      }
    }
    const __hip_bfloat16* sAr = smem + cur;
    const __hip_bfloat16* sAi = smem + cur + 4096;
    const __hip_bfloat16* sBc = smem + cur + 8192;
    const __hip_bfloat16* sBs = smem + cur + 12288;
    int krow = (lane >> 4) * 8;
    bf16x8 af[4], bfr[4];
#pragma unroll
    for (int mi = 0; mi < 4; ++mi)
      af[mi] = *(const bf16x8*)&sAr[(wmo + mi * 16 + (lane & 15)) * 32 + krow];
#pragma unroll
    for (int ni = 0; ni < 4; ++ni)
      bfr[ni] = *(const bf16x8*)&sBc[(wno + ni * 16 + (lane & 15)) * 32 + krow];
#pragma unroll
    for (int mi = 0; mi < 4; ++mi)
#pragma unroll
      for (int ni = 0; ni < 4; ++ni)
        aU[mi][ni] = __builtin_amdgcn_mfma_f32_16x16x32_bf16(
            af[mi], bfr[ni], aU[mi][ni], 0, 0, 0);
#pragma unroll
    for (int mi = 0; mi < 4; ++mi)
      af[mi] = *(const bf16x8*)&sAi[(wmo + mi * 16 + (lane & 15)) * 32 + krow];
#pragma unroll
    for (int ni = 0; ni < 4; ++ni)
      bfr[ni] = *(const bf16x8*)&sBs[(wno + ni * 16 + (lane & 15)) * 32 + krow];
#pragma unroll
    for (int mi = 0; mi < 4; ++mi)
#pragma unroll
      for (int ni = 0; ni < 4; ++ni)
        aV[mi][ni] = __builtin_amdgcn_mfma_f32_16x16x32_bf16(
            af[mi], bfr[ni], aV[mi][ni], 0, 0, 0);
    __syncthreads();                       // vmcnt(0)+lgkmcnt(0)+barrier: next tile ready
  }

  // epilogue: fragments -> LDS (reuse smem) -> coalesced bf16 stores
  __hip_bfloat16* fr0 = smem;
  __hip_bfloat16* fr1 = smem + 16384;
  float sn[4];
#pragma unroll
  for (int ni = 0; ni < 4; ++ni)
    sn[ni] = s_tab[N0 + wno + ni * 16 + (lane & 15)];
#pragma unroll
  for (int mi = 0; mi < 4; ++mi) {
#pragma unroll
    for (int r = 0; r < 4; ++r) {
      int rl = wmo + mi * 16 + (lane >> 4) * 4 + r;
      float rv = re512[M0 + rl];
#pragma unroll
      for (int ni = 0; ni < 4; ++ni) {
        int cl = wno + ni * 16 + (lane & 15);
        float U = aU[mi][ni][r], V = aV[mi][ni][r];
        float add = rv * sn[ni];
        fr0[rl * 128 + cl] = __float2bfloat16(U - V + add);
        fr1[rl * 128 + (127 - cl)] = __float2bfloat16(U + V + add);
      }
    }
  }
  __syncthreads();
  int row = tid >> 1;
  int hb = (tid & 1) * 64;
  size_t m = (size_t)(M0 + row);
  const int4* src0 = (const int4*)&fr0[row * 128 + hb];
  const int4* src1 = (const int4*)&fr1[row * 128 + hb];
  int4* d0 = (int4*)(frames0 + m * 512 + N0 + hb);
  int4* d1 = (int4*)(frames1 + m * 512 + (384 - N0) + hb);
#pragma unroll
  for (int c = 0; c < 8; ++c) { d0[c] = src0[c]; d1[c] = src1[c]; }
}

// out[b][l] = sum_t frame[t][l-256t]; j<512 -> frames0[m][j], j==512 -> fr512[m],
// j>512 -> frames1[m][j-513]
__global__ void ola(const __hip_bfloat16* __restrict__ frames0,
                    const __hip_bfloat16* __restrict__ frames1,
                    const float* __restrict__ fr512, float* __restrict__ out, int total) {
  int idx = blockIdx.x * blockDim.x + threadIdx.x;
  int stride = gridDim.x * blockDim.x;
  for (; idx < total; idx += stride) {
    int b = idx / LOUT;
    int l = idx - b * LOUT;
    int thi = l >> 8; if (thi > NT - 1) thi = NT - 1;
    int tlo = (l - 768) >> 8; if (tlo < 0) tlo = 0;
    float s = 0.f;
    for (int t = tlo; t <= thi; ++t) {
      int j = l - (t << 8);
      size_t m = (size_t)b * NT + t;
      if (j < 512) s += __bfloat162float(frames0[m * 512 + j]);
      else if (j > 512) s += __bfloat162float(frames1[m * 512 + (j - 513)]);
      else s += fr512[m];
    }
    out[idx] = s;
  }
}

extern "C" void kernel_launch(void* const* d_in, const int* in_sizes, int n_in,
                              void* d_out, int out_size, void* d_ws, size_t ws_size,
                              hipStream_t stream) {
  (void)in_sizes; (void)n_in; (void)out_size; (void)ws_size;
  const float* x = (const float*)d_in[0];
  float* out = (float*)d_out;
  char* ws = (char*)d_ws;
  size_t oAre = 0;
  size_t oAim = oAre + (size_t)MM * KA * 2;
  size_t oBc  = oAim + (size_t)MM * KA * 2;
  size_t oBs  = oBc + (size_t)512 * 512 * 2;
  size_t oS   = oBs + (size_t)512 * 512 * 2;
  size_t oR5  = oS + 512 * 4;
  size_t oF5  = oR5 + (size_t)MM * 4;
  size_t oF0  = oF5 + (size_t)MM * 4;
  size_t oF1  = oF0 + (size_t)MM * 512 * 2;
  __hip_bfloat16* Are = (__hip_bfloat16*)(ws + oAre);
  __hip_bfloat16* Aim = (__hip_bfloat16*)(ws + oAim);
  __hip_bfloat16* Bc  = (__hip_bfloat16*)(ws + oBc);
  __hip_bfloat16* Bs  = (__hip_bfloat16*)(ws + oBs);
  float* s_tab = (float*)(ws + oS);
  float* re512 = (float*)(ws + oR5);
  float* fr512 = (float*)(ws + oF5);
  __hip_bfloat16* frames0 = (__hip_bfloat16*)(ws + oF0);
  __hip_bfloat16* frames1 = (__hip_bfloat16*)(ws + oF1);

  build_B<<<dim3(512 * 512 / 256), dim3(256), 0, stream>>>(Bc, Bs, s_tab);
  pack_a<<<dim3(16, 8, 16), dim3(256), 0, stream>>>(x, Are, Aim, re512);
  nyq<<<dim3(MM / 4), dim3(256), 0, stream>>>(Are, re512, fr512);
  gemm_uv<<<dim3(MM / 128, 4), dim3(256), 0, stream>>>(Are, Aim, Bc, Bs, re512, s_tab,
                                                       frames0, frames1);
  ola<<<dim3(2048), dim3(256), 0, stream>>>(frames0, frames1, fr512, out, NB * LOUT);
}